// Round 2
// baseline (4861.820 us; speedup 1.0000x reference)
//
#include <hip/hip_runtime.h>
#include <hip/hip_bf16.h>
#include <math.h>

// Problem constants
#define V  32000
#define TT 1024      // context length
#define DD 1024      // embed dim
#define HH 16        // heads
#define HDIM 64      // head dim
#define LL 6         // layers
#define BB 2         // batch
#define MM (BB*TT)   // 2048 rows

typedef __attribute__((ext_vector_type(8))) short bf16x8;
typedef __attribute__((ext_vector_type(4))) float f32x4;

// split fp32 -> bf16 hi + bf16 lo (RNE both), x ~= hi + lo to ~2^-17 rel
__device__ __forceinline__ void split2(float x, ushort& hi, ushort& lo) {
    union { float f; unsigned u; } a; a.f = x;
    unsigned r = a.u + 0x7FFFu + ((a.u >> 16) & 1u);
    hi = (ushort)(r >> 16);
    union { unsigned u; float f; } hf; hf.u = ((unsigned)hi) << 16;
    float rem = x - hf.f;
    union { float f; unsigned u; } b; b.f = rem;
    unsigned r2 = b.u + 0x7FFFu + ((b.u >> 16) & 1u);
    lo = (ushort)(r2 >> 16);
}

// ---------------- Embedding ----------------
__global__ __launch_bounds__(256) void embed_kernel(
    const int* __restrict__ tokens, const float* __restrict__ te,
    const float* __restrict__ pe, float* __restrict__ h)
{
    int row = blockIdx.x;
    int t = row & (TT - 1);
    int tok = tokens[row];
    int tid = threadIdx.x;
    const float4 a = *(const float4*)(te + (size_t)tok * DD + tid * 4);
    const float4 p = *(const float4*)(pe + (size_t)t * DD + tid * 4);
    float4 o;
    o.x = a.x + p.x; o.y = a.y + p.y; o.z = a.z + p.z; o.w = a.w + p.w;
    *(float4*)(h + (size_t)row * DD + tid * 4) = o;
}

// ---------------- LayerNorm ----------------
__global__ __launch_bounds__(256) void ln_kernel(
    const float* __restrict__ in, size_t instride,
    const float* __restrict__ w, const float* __restrict__ b,
    float* __restrict__ out, size_t outstride)
{
    int row = blockIdx.x;
    const float* x = in + (size_t)row * instride;
    float* y = out + (size_t)row * outstride;
    int tid = threadIdx.x;
    float4 v = *(const float4*)(x + tid * 4);
    float s  = v.x + v.y + v.z + v.w;
    float sq = v.x*v.x + v.y*v.y + v.z*v.z + v.w*v.w;
    #pragma unroll
    for (int off = 32; off > 0; off >>= 1) {
        s  += __shfl_down(s, off);
        sq += __shfl_down(sq, off);
    }
    __shared__ float red[8];
    int wid = tid >> 6;
    if ((tid & 63) == 0) { red[wid*2] = s; red[wid*2+1] = sq; }
    __syncthreads();
    s  = red[0] + red[2] + red[4] + red[6];
    sq = red[1] + red[3] + red[5] + red[7];
    float mu  = s * (1.0f / DD);
    float var = sq * (1.0f / DD) - mu * mu;
    float rs  = rsqrtf(var + 1e-5f);
    float4 wv = *(const float4*)(w + tid * 4);
    float4 bv = *(const float4*)(b + tid * 4);
    float4 o;
    o.x = (v.x - mu) * rs * wv.x + bv.x;
    o.y = (v.y - mu) * rs * wv.y + bv.y;
    o.z = (v.z - mu) * rs * wv.z + bv.z;
    o.w = (v.w - mu) * rs * wv.w + bv.w;
    *(float4*)(y + tid * 4) = o;
}

// ---------------- Weight transpose + split: W[K][N] fp32 -> Wt_hi/lo[N][K] bf16 ----------------
__global__ __launch_bounds__(256) void transpose_split(
    const float* __restrict__ W, ushort* __restrict__ Wt_hi,
    ushort* __restrict__ Wt_lo, int K, int N)
{
    __shared__ float tile[64][65];
    int n0 = blockIdx.x * 64, k0 = blockIdx.y * 64;
    int tx = threadIdx.x & 63, ty = threadIdx.x >> 6;  // ty 0..3
    #pragma unroll
    for (int i = 0; i < 16; ++i) {
        int k = i * 4 + ty;
        tile[k][tx] = W[(size_t)(k0 + k) * N + n0 + tx];
    }
    __syncthreads();
    #pragma unroll
    for (int i = 0; i < 16; ++i) {
        int n = i * 4 + ty;
        float v = tile[tx][n];
        ushort hi, lo;
        split2(v, hi, lo);
        size_t o = (size_t)(n0 + n) * K + k0 + tx;
        Wt_hi[o] = hi;
        Wt_lo[o] = lo;
    }
}

// ---------------- Split-bf16 MFMA GEMM: C = A[MxK]fp32 @ Bt[N][K](hi+lo) + bias (+res) ----------------
// 128x128 tile, BK=64, 256 threads = 4 waves (2x2), 64x64 per wave, 4x4 frags of 16x16x32.
__global__ __launch_bounds__(256, 2) void gemm_split(
    const float* __restrict__ A, const ushort* __restrict__ Bt_hi,
    const ushort* __restrict__ Bt_lo, const float* __restrict__ bias,
    const float* __restrict__ res, float* __restrict__ C,
    int M, int N, int K)
{
    __shared__ alignas(16) ushort As_hi[128 * 64];
    __shared__ alignas(16) ushort As_lo[128 * 64];
    __shared__ alignas(16) ushort Bs_hi[128 * 64];
    __shared__ alignas(16) ushort Bs_lo[128 * 64];

    int tid = threadIdx.x;
    int bx = blockIdx.x, by = blockIdx.y;
    int lane = tid & 63, w = tid >> 6;
    int wr = w >> 1, wc = w & 1;

    f32x4 zero = {0.f, 0.f, 0.f, 0.f};
    f32x4 acc[4][4];
    #pragma unroll
    for (int m = 0; m < 4; ++m)
        #pragma unroll
        for (int n = 0; n < 4; ++n) acc[m][n] = zero;

    for (int k0 = 0; k0 < K; k0 += 64) {
        // stage A (fp32 -> split bf16), swizzled LDS layout
        #pragma unroll
        for (int i = 0; i < 8; ++i) {
            int f = tid + i * 256;          // 2048 float4 = 128x64 tile
            int r = f >> 4, k4 = f & 15;
            float4 v = *(const float4*)(A + (size_t)(by * 128 + r) * K + k0 + k4 * 4);
            ushort h0, h1, h2, h3, l0, l1, l2, l3;
            split2(v.x, h0, l0); split2(v.y, h1, l1);
            split2(v.z, h2, l2); split2(v.w, h3, l3);
            int idx = r * 64 + (((k4 >> 1) ^ (r & 7)) << 3) + ((k4 & 1) << 2);
            *(ushort4*)&As_hi[idx] = make_ushort4(h0, h1, h2, h3);
            *(ushort4*)&As_lo[idx] = make_ushort4(l0, l1, l2, l3);
        }
        // stage B (already bf16 hi/lo, [N][K] layout -> coalesced)
        #pragma unroll
        for (int i = 0; i < 8; ++i) {
            int f = tid + i * 256;
            int r = f >> 4, k4 = f & 15;
            size_t g = (size_t)(bx * 128 + r) * K + k0 + k4 * 4;
            ushort4 vh = *(const ushort4*)(Bt_hi + g);
            ushort4 vl = *(const ushort4*)(Bt_lo + g);
            int idx = r * 64 + (((k4 >> 1) ^ (r & 7)) << 3) + ((k4 & 1) << 2);
            *(ushort4*)&Bs_hi[idx] = vh;
            *(ushort4*)&Bs_lo[idx] = vl;
        }
        __syncthreads();

        #pragma unroll
        for (int ks = 0; ks < 2; ++ks) {
            bf16x8 ah[4], al[4], bh[4], bl[4];
            #pragma unroll
            for (int m = 0; m < 4; ++m) {
                int r = wr * 64 + m * 16 + (lane & 15);
                int c = (ks * 4 + (lane >> 4)) ^ (r & 7);
                int idx = r * 64 + c * 8;
                ah[m] = *(bf16x8*)&As_hi[idx];
                al[m] = *(bf16x8*)&As_lo[idx];
            }
            #pragma unroll
            for (int n = 0; n < 4; ++n) {
                int r = wc * 64 + n * 16 + (lane & 15);
                int c = (ks * 4 + (lane >> 4)) ^ (r & 7);
                int idx = r * 64 + c * 8;
                bh[n] = *(bf16x8*)&Bs_hi[idx];
                bl[n] = *(bf16x8*)&Bs_lo[idx];
            }
            #pragma unroll
            for (int m = 0; m < 4; ++m)
                #pragma unroll
                for (int n = 0; n < 4; ++n) {
                    acc[m][n] = __builtin_amdgcn_mfma_f32_16x16x32_bf16(ah[m], bh[n], acc[m][n], 0, 0, 0);
                    acc[m][n] = __builtin_amdgcn_mfma_f32_16x16x32_bf16(ah[m], bl[n], acc[m][n], 0, 0, 0);
                    acc[m][n] = __builtin_amdgcn_mfma_f32_16x16x32_bf16(al[m], bh[n], acc[m][n], 0, 0, 0);
                }
        }
        __syncthreads();
    }

    // epilogue: C[row][col] = acc + bias[col] (+ res[row][col])
    int cf = lane & 15;        // col within frag (verified C layout)
    int rf = (lane >> 4) * 4;  // row base within frag
    #pragma unroll
    for (int n = 0; n < 4; ++n) {
        int col = bx * 128 + wc * 64 + n * 16 + cf;
        float bv = bias[col];
        #pragma unroll
        for (int m = 0; m < 4; ++m) {
            int row0 = by * 128 + wr * 64 + m * 16 + rf;
            #pragma unroll
            for (int r = 0; r < 4; ++r) {
                float vout = acc[m][n][r] + bv;
                size_t o = (size_t)(row0 + r) * N + col;
                if (res) vout += res[o];
                C[o] = vout;
            }
        }
    }
}

// ---------------- Flash attention (fp32, online softmax) ----------------
#define KB 128
__global__ __launch_bounds__(128) void attn_kernel(
    const float* __restrict__ qkv, float* __restrict__ o)
{
    __shared__ float Ks[KB][HDIM];
    __shared__ float Vs[KB][HDIM];
    int bh = blockIdx.x;
    int b = bh >> 4, hh = bh & 15;
    int qb = blockIdx.y;
    int t = threadIdx.x;
    int qg = qb * 128 + t;
    const float* base = qkv + (size_t)b * TT * (3 * DD);

    float q[HDIM];
    {
        const float* qrow = base + (size_t)qg * (3 * DD) + hh * HDIM;
        #pragma unroll
        for (int i = 0; i < 16; ++i)
            *(float4*)&q[i * 4] = *(const float4*)(qrow + i * 4);
    }
    float m = -1e30f, l = 0.f;
    float acc[HDIM];
    #pragma unroll
    for (int d = 0; d < HDIM; ++d) acc[d] = 0.f;
    const float scale = 0.125f;

    for (int kt = 0; kt <= qb; ++kt) {
        int ks = kt * KB;
        const float* krow = base + (size_t)(ks + t) * (3 * DD) + DD + hh * HDIM;
        const float* vrow = krow + DD;
        #pragma unroll
        for (int i = 0; i < 16; ++i) {
            *(float4*)&Ks[t][i * 4] = *(const float4*)(krow + i * 4);
            *(float4*)&Vs[t][i * 4] = *(const float4*)(vrow + i * 4);
        }
        __syncthreads();
        int kmax = min(KB, qg - ks + 1);
        for (int k = 0; k < kmax; ++k) {
            float s0 = 0, s1 = 0, s2 = 0, s3 = 0;
            const float* kp = Ks[k];
            #pragma unroll
            for (int i = 0; i < 16; ++i) {
                float4 kv = *(const float4*)(kp + i * 4);
                s0 += q[i*4+0] * kv.x; s1 += q[i*4+1] * kv.y;
                s2 += q[i*4+2] * kv.z; s3 += q[i*4+3] * kv.w;
            }
            float s = ((s0 + s1) + (s2 + s3)) * scale;
            if (s > m) {
                float corr = __expf(m - s);
                l *= corr;
                #pragma unroll
                for (int d = 0; d < HDIM; ++d) acc[d] *= corr;
                m = s;
            }
            float p = __expf(s - m);
            l += p;
            const float* vp = Vs[k];
            #pragma unroll
            for (int i = 0; i < 16; ++i) {
                float4 vv = *(const float4*)(vp + i * 4);
                acc[i*4+0] += p * vv.x; acc[i*4+1] += p * vv.y;
                acc[i*4+2] += p * vv.z; acc[i*4+3] += p * vv.w;
            }
        }
        __syncthreads();
    }
    float inv = 1.f / l;
    float* orow = o + (size_t)(b * TT + qg) * DD + hh * HDIM;
    #pragma unroll
    for (int i = 0; i < 16; ++i) {
        float4 r;
        r.x = acc[i*4+0] * inv; r.y = acc[i*4+1] * inv;
        r.z = acc[i*4+2] * inv; r.w = acc[i*4+3] * inv;
        *(float4*)(orow + i * 4) = r;
    }
}

// ---------------- Vocab head ----------------
__global__ __launch_bounds__(256) void head_kernel(
    const float* __restrict__ xf, const float* __restrict__ Wh,
    const float* __restrict__ bh, float* __restrict__ out)
{
    __shared__ float x0[DD];
    __shared__ float x1[DD];
    int tid = threadIdx.x;
    for (int i = tid; i < DD; i += 256) {
        x0[i] = xf[i];
        x1[i] = xf[DD + i];
    }
    __syncthreads();
    int v = blockIdx.x * 256 + tid;
    float a0 = 0.f, a1 = 0.f, a0b = 0.f, a1b = 0.f;
    for (int d = 0; d < DD; d += 2) {
        float w0 = Wh[(size_t)d * V + v];
        float w1 = Wh[(size_t)(d + 1) * V + v];
        a0  += x0[d] * w0;     a1  += x1[d] * w0;
        a0b += x0[d + 1] * w1; a1b += x1[d + 1] * w1;
    }
    out[v]      = a0 + a0b + bh[v];
    out[V + v]  = a1 + a1b + bh[v];
}

// ---------------- Launch ----------------
extern "C" void kernel_launch(void* const* d_in, const int* in_sizes, int n_in,
                              void* d_out, int out_size, void* d_ws, size_t ws_size,
                              hipStream_t stream) {
    const int*   tokens  = (const int*)d_in[0];
    const float* te      = (const float*)d_in[1];
    const float* pe      = (const float*)d_in[2];
    const float* qkv_w   = (const float*)d_in[3];
    const float* qkv_b   = (const float*)d_in[4];
    const float* out_w   = (const float*)d_in[5];
    const float* out_b   = (const float*)d_in[6];
    const float* ln_w    = (const float*)d_in[7];
    const float* ln_b    = (const float*)d_in[8];
    const float* lnf_w   = (const float*)d_in[9];
    const float* lnf_b   = (const float*)d_in[10];
    const float* head_w  = (const float*)d_in[11];
    const float* head_b  = (const float*)d_in[12];
    float* logits = (float*)d_out;

    // workspace layout (~67 MB):
    float* h    = (float*)d_ws;                       // 2048x1024
    float* x    = h + (size_t)MM * DD;                // 2048x1024
    float* qkvb = x + (size_t)MM * DD;                // 2048x3072
    float* ob   = qkvb + (size_t)MM * 3 * DD;         // 2048x1024
    float* xfin = ob + (size_t)MM * DD;               // 2x1024
    ushort* wq_hi = (ushort*)(xfin + 2 * DD);         // 3072x1024 bf16
    ushort* wq_lo = wq_hi + (size_t)3 * DD * DD;
    ushort* wo_hi = wq_lo + (size_t)3 * DD * DD;      // 1024x1024 bf16
    ushort* wo_lo = wo_hi + (size_t)DD * DD;

    embed_kernel<<<MM, 256, 0, stream>>>(tokens, te, pe, h);

    for (int l = 0; l < LL; ++l) {
        transpose_split<<<dim3(3 * DD / 64, DD / 64), 256, 0, stream>>>(
            qkv_w + (size_t)l * DD * 3 * DD, wq_hi, wq_lo, DD, 3 * DD);
        transpose_split<<<dim3(DD / 64, DD / 64), 256, 0, stream>>>(
            out_w + (size_t)l * DD * DD, wo_hi, wo_lo, DD, DD);

        ln_kernel<<<MM, 256, 0, stream>>>(h, DD, ln_w + (size_t)l * DD,
                                          ln_b + (size_t)l * DD, x, DD);
        gemm_split<<<dim3(3 * DD / 128, MM / 128), 256, 0, stream>>>(
            x, wq_hi, wq_lo, qkv_b + (size_t)l * 3 * DD, nullptr, qkvb,
            MM, 3 * DD, DD);
        attn_kernel<<<dim3(BB * HH, TT / 128), 128, 0, stream>>>(qkvb, ob);
        gemm_split<<<dim3(DD / 128, MM / 128), 256, 0, stream>>>(
            ob, wo_hi, wo_lo, out_b + (size_t)l * DD, h, h, MM, DD, DD);
    }

    ln_kernel<<<2, 256, 0, stream>>>(h + (size_t)(TT - 1) * DD, (size_t)TT * DD,
                                     lnf_w, lnf_b, xfin, DD);
    head_kernel<<<V / 256, 256, 0, stream>>>(xfin, head_w, head_b, logits);
}

// Round 3
// 1421.635 us; speedup vs baseline: 3.4199x; 3.4199x over previous
//
#include <hip/hip_runtime.h>
#include <hip/hip_bf16.h>
#include <math.h>

// Problem constants
#define V  32000
#define TT 1024      // context length
#define DD 1024      // embed dim
#define HH 16        // heads
#define HDIM 64      // head dim
#define LL 6         // layers
#define BB 2         // batch
#define MM (BB*TT)   // 2048 rows

typedef __attribute__((ext_vector_type(8))) short bf16x8;
typedef __attribute__((ext_vector_type(4))) float f32x4;

// split fp32 -> bf16 hi + bf16 lo (RNE both), x ~= hi + lo to ~2^-17 rel
__device__ __forceinline__ void split2(float x, ushort& hi, ushort& lo) {
    union { float f; unsigned u; } a; a.f = x;
    unsigned r = a.u + 0x7FFFu + ((a.u >> 16) & 1u);
    hi = (ushort)(r >> 16);
    union { unsigned u; float f; } hf; hf.u = ((unsigned)hi) << 16;
    float rem = x - hf.f;
    union { float f; unsigned u; } b; b.f = rem;
    unsigned r2 = b.u + 0x7FFFu + ((b.u >> 16) & 1u);
    lo = (ushort)(r2 >> 16);
}

// ---------------- Embedding ----------------
__global__ __launch_bounds__(256) void embed_kernel(
    const int* __restrict__ tokens, const float* __restrict__ te,
    const float* __restrict__ pe, float* __restrict__ h)
{
    int row = blockIdx.x;
    int t = row & (TT - 1);
    int tok = tokens[row];
    int tid = threadIdx.x;
    const float4 a = *(const float4*)(te + (size_t)tok * DD + tid * 4);
    const float4 p = *(const float4*)(pe + (size_t)t * DD + tid * 4);
    float4 o;
    o.x = a.x + p.x; o.y = a.y + p.y; o.z = a.z + p.z; o.w = a.w + p.w;
    *(float4*)(h + (size_t)row * DD + tid * 4) = o;
}

// ---------------- LayerNorm ----------------
__global__ __launch_bounds__(256) void ln_kernel(
    const float* __restrict__ in, size_t instride,
    const float* __restrict__ w, const float* __restrict__ b,
    float* __restrict__ out, size_t outstride)
{
    int row = blockIdx.x;
    const float* x = in + (size_t)row * instride;
    float* y = out + (size_t)row * outstride;
    int tid = threadIdx.x;
    float4 v = *(const float4*)(x + tid * 4);
    float s  = v.x + v.y + v.z + v.w;
    float sq = v.x*v.x + v.y*v.y + v.z*v.z + v.w*v.w;
    #pragma unroll
    for (int off = 32; off > 0; off >>= 1) {
        s  += __shfl_down(s, off);
        sq += __shfl_down(sq, off);
    }
    __shared__ float red[8];
    int wid = tid >> 6;
    if ((tid & 63) == 0) { red[wid*2] = s; red[wid*2+1] = sq; }
    __syncthreads();
    s  = red[0] + red[2] + red[4] + red[6];
    sq = red[1] + red[3] + red[5] + red[7];
    float mu  = s * (1.0f / DD);
    float var = sq * (1.0f / DD) - mu * mu;
    float rs  = rsqrtf(var + 1e-5f);
    float4 wv = *(const float4*)(w + tid * 4);
    float4 bv = *(const float4*)(b + tid * 4);
    float4 o;
    o.x = (v.x - mu) * rs * wv.x + bv.x;
    o.y = (v.y - mu) * rs * wv.y + bv.y;
    o.z = (v.z - mu) * rs * wv.z + bv.z;
    o.w = (v.w - mu) * rs * wv.w + bv.w;
    *(float4*)(y + tid * 4) = o;
}

// ---------------- Weight transpose + split: W[K][N] fp32 -> Wt_hi/lo[N][K] bf16 ----------------
__global__ __launch_bounds__(256) void transpose_split(
    const float* __restrict__ W, ushort* __restrict__ Wt_hi,
    ushort* __restrict__ Wt_lo, int K, int N)
{
    __shared__ float tile[64][65];
    int n0 = blockIdx.x * 64, k0 = blockIdx.y * 64;
    int tx = threadIdx.x & 63, ty = threadIdx.x >> 6;  // ty 0..3
    #pragma unroll
    for (int i = 0; i < 16; ++i) {
        int k = i * 4 + ty;
        tile[k][tx] = W[(size_t)(k0 + k) * N + n0 + tx];
    }
    __syncthreads();
    #pragma unroll
    for (int i = 0; i < 16; ++i) {
        int n = i * 4 + ty;
        float v = tile[tx][n];
        ushort hi, lo;
        split2(v, hi, lo);
        size_t o = (size_t)(n0 + n) * K + k0 + tx;
        Wt_hi[o] = hi;
        Wt_lo[o] = lo;
    }
}

// ---------------- Split-bf16 MFMA GEMM (unchanged from round 2, passed) ----------------
#define BM 128
#define BN 128
__global__ __launch_bounds__(256, 2) void gemm_split(
    const float* __restrict__ A, const ushort* __restrict__ Bt_hi,
    const ushort* __restrict__ Bt_lo, const float* __restrict__ bias,
    const float* __restrict__ res, float* __restrict__ C,
    int M, int N, int K)
{
    __shared__ alignas(16) ushort As_hi[128 * 64];
    __shared__ alignas(16) ushort As_lo[128 * 64];
    __shared__ alignas(16) ushort Bs_hi[128 * 64];
    __shared__ alignas(16) ushort Bs_lo[128 * 64];

    int tid = threadIdx.x;
    int bx = blockIdx.x, by = blockIdx.y;
    int lane = tid & 63, w = tid >> 6;
    int wr = w >> 1, wc = w & 1;

    f32x4 zero = {0.f, 0.f, 0.f, 0.f};
    f32x4 acc[4][4];
    #pragma unroll
    for (int m = 0; m < 4; ++m)
        #pragma unroll
        for (int n = 0; n < 4; ++n) acc[m][n] = zero;

    for (int k0 = 0; k0 < K; k0 += 64) {
        #pragma unroll
        for (int i = 0; i < 8; ++i) {
            int f = tid + i * 256;
            int r = f >> 4, k4 = f & 15;
            float4 v = *(const float4*)(A + (size_t)(by * 128 + r) * K + k0 + k4 * 4);
            ushort h0, h1, h2, h3, l0, l1, l2, l3;
            split2(v.x, h0, l0); split2(v.y, h1, l1);
            split2(v.z, h2, l2); split2(v.w, h3, l3);
            int idx = r * 64 + (((k4 >> 1) ^ (r & 7)) << 3) + ((k4 & 1) << 2);
            *(ushort4*)&As_hi[idx] = make_ushort4(h0, h1, h2, h3);
            *(ushort4*)&As_lo[idx] = make_ushort4(l0, l1, l2, l3);
        }
        #pragma unroll
        for (int i = 0; i < 8; ++i) {
            int f = tid + i * 256;
            int r = f >> 4, k4 = f & 15;
            size_t g = (size_t)(bx * 128 + r) * K + k0 + k4 * 4;
            ushort4 vh = *(const ushort4*)(Bt_hi + g);
            ushort4 vl = *(const ushort4*)(Bt_lo + g);
            int idx = r * 64 + (((k4 >> 1) ^ (r & 7)) << 3) + ((k4 & 1) << 2);
            *(ushort4*)&Bs_hi[idx] = vh;
            *(ushort4*)&Bs_lo[idx] = vl;
        }
        __syncthreads();

        #pragma unroll
        for (int ks = 0; ks < 2; ++ks) {
            bf16x8 ah[4], al[4], bh[4], bl[4];
            #pragma unroll
            for (int m = 0; m < 4; ++m) {
                int r = wr * 64 + m * 16 + (lane & 15);
                int c = (ks * 4 + (lane >> 4)) ^ (r & 7);
                int idx = r * 64 + c * 8;
                ah[m] = *(bf16x8*)&As_hi[idx];
                al[m] = *(bf16x8*)&As_lo[idx];
            }
            #pragma unroll
            for (int n = 0; n < 4; ++n) {
                int r = wc * 64 + n * 16 + (lane & 15);
                int c = (ks * 4 + (lane >> 4)) ^ (r & 7);
                int idx = r * 64 + c * 8;
                bh[n] = *(bf16x8*)&Bs_hi[idx];
                bl[n] = *(bf16x8*)&Bs_lo[idx];
            }
            #pragma unroll
            for (int m = 0; m < 4; ++m)
                #pragma unroll
                for (int n = 0; n < 4; ++n) {
                    acc[m][n] = __builtin_amdgcn_mfma_f32_16x16x32_bf16(ah[m], bh[n], acc[m][n], 0, 0, 0);
                    acc[m][n] = __builtin_amdgcn_mfma_f32_16x16x32_bf16(ah[m], bl[n], acc[m][n], 0, 0, 0);
                    acc[m][n] = __builtin_amdgcn_mfma_f32_16x16x32_bf16(al[m], bh[n], acc[m][n], 0, 0, 0);
                }
        }
        __syncthreads();
    }

    int cf = lane & 15;
    int rf = (lane >> 4) * 4;
    #pragma unroll
    for (int n = 0; n < 4; ++n) {
        int col = bx * 128 + wc * 64 + n * 16 + cf;
        float bv = bias[col];
        #pragma unroll
        for (int m = 0; m < 4; ++m) {
            int row0 = by * 128 + wr * 64 + m * 16 + rf;
            #pragma unroll
            for (int r = 0; r < 4; ++r) {
                float vout = acc[m][n][r] + bv;
                size_t o = (size_t)(row0 + r) * N + col;
                if (res) vout += res[o];
                C[o] = vout;
            }
        }
    }
}

// ---------------- V transpose+split: qkv v-part -> Vt[bh][d][t] bf16 hi/lo ----------------
__global__ __launch_bounds__(256) void v_transpose_split(
    const float* __restrict__ qkv, ushort* __restrict__ vt_hi,
    ushort* __restrict__ vt_lo)
{
    __shared__ float tile[64][65];
    int bh = blockIdx.x, b = bh >> 4, h = bh & 15;
    int t0 = blockIdx.y * 64;
    int tid = threadIdx.x;
    #pragma unroll
    for (int i = 0; i < 4; ++i) {
        int f = tid + i * 256;          // 0..1023
        int r = f >> 4, c4 = f & 15;
        float4 v = *(const float4*)(qkv + (size_t)(b * TT + t0 + r) * 3072
                                    + 2048 + h * 64 + c4 * 4);
        tile[r][c4 * 4 + 0] = v.x; tile[r][c4 * 4 + 1] = v.y;
        tile[r][c4 * 4 + 2] = v.z; tile[r][c4 * 4 + 3] = v.w;
    }
    __syncthreads();
    #pragma unroll
    for (int i = 0; i < 4; ++i) {
        int f = tid + i * 256;
        int d = f >> 4, tq = (f & 15) * 4;
        ushort4 hi, lo;
        split2(tile[tq + 0][d], hi.x, lo.x);
        split2(tile[tq + 1][d], hi.y, lo.y);
        split2(tile[tq + 2][d], hi.z, lo.z);
        split2(tile[tq + 3][d], hi.w, lo.w);
        size_t o = ((size_t)bh * 64 + d) * TT + t0 + tq;
        *(ushort4*)(vt_hi + o) = hi;
        *(ushort4*)(vt_lo + o) = lo;
    }
}

// ---------------- MFMA flash attention, fp32-equivalent via hi/lo split ----------------
// grid (B*H, T/64); block 256 = 4 waves; wave w owns q-rows [q0+16w, q0+16w+16)
__global__ __launch_bounds__(256) void attn_mfma(
    const float* __restrict__ qkv, const ushort* __restrict__ vt_hi,
    const ushort* __restrict__ vt_lo, float* __restrict__ o)
{
    __shared__ alignas(16) ushort Ks_hi[64 * 64];
    __shared__ alignas(16) ushort Ks_lo[64 * 64];
    __shared__ alignas(16) ushort Vs_hi[64 * 64];
    __shared__ alignas(16) ushort Vs_lo[64 * 64];
    __shared__ alignas(16) ushort Ph[4][16 * 64];
    __shared__ alignas(16) ushort Pl[4][16 * 64];

    int bh = blockIdx.x, b = bh >> 4, h = bh & 15;
    int q0 = (int)(gridDim.y - 1 - blockIdx.y) * 64;   // longest blocks first
    int tid = threadIdx.x, lane = tid & 63, w = tid >> 6;
    int lm = lane & 15, lg = lane >> 4;

    int qrow = q0 + w * 16 + lm;                       // this lane's q (S^T col)
    // preload Q fragments (fp32 -> split bf16), ks = 0,1
    bf16x8 Qh[2], Ql[2];
    {
        const float* qptr = qkv + (size_t)(b * TT + qrow) * 3072 + h * 64;
        #pragma unroll
        for (int ks = 0; ks < 2; ++ks) {
            int d0 = ks * 32 + lg * 8;
            float4 a = *(const float4*)(qptr + d0);
            float4 c = *(const float4*)(qptr + d0 + 4);
            ushort hi, lo;
            split2(a.x, hi, lo); Qh[ks][0] = hi; Ql[ks][0] = lo;
            split2(a.y, hi, lo); Qh[ks][1] = hi; Ql[ks][1] = lo;
            split2(a.z, hi, lo); Qh[ks][2] = hi; Ql[ks][2] = lo;
            split2(a.w, hi, lo); Qh[ks][3] = hi; Ql[ks][3] = lo;
            split2(c.x, hi, lo); Qh[ks][4] = hi; Ql[ks][4] = lo;
            split2(c.y, hi, lo); Qh[ks][5] = hi; Ql[ks][5] = lo;
            split2(c.z, hi, lo); Qh[ks][6] = hi; Ql[ks][6] = lo;
            split2(c.w, hi, lo); Qh[ks][7] = hi; Ql[ks][7] = lo;
        }
    }

    f32x4 acc[4];                    // O: col d = n*16+lm, row q = lg*4+reg
    #pragma unroll
    for (int n = 0; n < 4; ++n) acc[n] = (f32x4){0.f, 0.f, 0.f, 0.f};
    float mrow = -1e30f, lsum = 0.f;
    const float scale = 0.125f;
    int ktmax = q0 >> 6;

    for (int kt = 0; kt <= ktmax; ++kt) {
        int k0 = kt * 64;
        // ---- stage K (fp32 -> split bf16, swizzled) ----
        #pragma unroll
        for (int i = 0; i < 4; ++i) {
            int f = tid + i * 256;
            int r = f >> 4, c4 = f & 15;
            float4 v = *(const float4*)(qkv + (size_t)(b * TT + k0 + r) * 3072
                                        + 1024 + h * 64 + c4 * 4);
            ushort h0, h1, h2, h3, l0, l1, l2, l3;
            split2(v.x, h0, l0); split2(v.y, h1, l1);
            split2(v.z, h2, l2); split2(v.w, h3, l3);
            int idx = r * 64 + (((c4 >> 1) ^ (r & 7)) << 3) + ((c4 & 1) << 2);
            *(ushort4*)&Ks_hi[idx] = make_ushort4(h0, h1, h2, h3);
            *(ushort4*)&Ks_lo[idx] = make_ushort4(l0, l1, l2, l3);
        }
        // ---- stage Vt (bf16 copy, swizzled) ----
        #pragma unroll
        for (int i = 0; i < 2; ++i) {
            int f = tid + i * 256;          // 0..511 chunks of 8 ushorts
            int d = f >> 3, c = f & 7;
            size_t g = ((size_t)bh * 64 + d) * TT + k0 + c * 8;
            bf16x8 vh = *(const bf16x8*)(vt_hi + g);
            bf16x8 vl = *(const bf16x8*)(vt_lo + g);
            int idx = d * 64 + ((c ^ (d & 7)) << 3);
            *(bf16x8*)&Vs_hi[idx] = vh;
            *(bf16x8*)&Vs_lo[idx] = vl;
        }
        __syncthreads();

        // ---- S^T = K @ Q^T : rows k (4 frags), cols q ----
        f32x4 s[4];
        #pragma unroll
        for (int m = 0; m < 4; ++m) s[m] = (f32x4){0.f, 0.f, 0.f, 0.f};
        #pragma unroll
        for (int ks = 0; ks < 2; ++ks) {
            #pragma unroll
            for (int m = 0; m < 4; ++m) {
                int kr = m * 16 + lm;
                int ch = (ks * 4 + lg) ^ (kr & 7);
                int idx = kr * 64 + ch * 8;
                bf16x8 kh = *(bf16x8*)&Ks_hi[idx];
                bf16x8 kl = *(bf16x8*)&Ks_lo[idx];
                s[m] = __builtin_amdgcn_mfma_f32_16x16x32_bf16(kh, Qh[ks], s[m], 0, 0, 0);
                s[m] = __builtin_amdgcn_mfma_f32_16x16x32_bf16(kh, Ql[ks], s[m], 0, 0, 0);
                s[m] = __builtin_amdgcn_mfma_f32_16x16x32_bf16(kl, Qh[ks], s[m], 0, 0, 0);
            }
        }
        // scale + causal mask (only the diagonal tile needs it)
        #pragma unroll
        for (int m = 0; m < 4; ++m)
            #pragma unroll
            for (int r = 0; r < 4; ++r) s[m][r] *= scale;
        if (kt == ktmax) {
            #pragma unroll
            for (int m = 0; m < 4; ++m)
                #pragma unroll
                for (int r = 0; r < 4; ++r)
                    if (k0 + m * 16 + lg * 4 + r > qrow) s[m][r] = -1e30f;
        }
        // ---- online softmax (lane's col q = lane&15; k spread over lg groups) ----
        float tmax = -1e30f;
        #pragma unroll
        for (int m = 0; m < 4; ++m) {
            tmax = fmaxf(tmax, fmaxf(fmaxf(s[m][0], s[m][1]), fmaxf(s[m][2], s[m][3])));
        }
        tmax = fmaxf(tmax, __shfl_xor(tmax, 16));
        tmax = fmaxf(tmax, __shfl_xor(tmax, 32));
        float mnew = fmaxf(mrow, tmax);
        float corr = __expf(mrow - mnew);
        mrow = mnew;
        float psum = 0.f;
        #pragma unroll
        for (int m = 0; m < 4; ++m) {
            float p0 = __expf(s[m][0] - mnew);
            float p1 = __expf(s[m][1] - mnew);
            float p2 = __expf(s[m][2] - mnew);
            float p3 = __expf(s[m][3] - mnew);
            psum += (p0 + p1) + (p2 + p3);
            ushort4 hi, lo;
            split2(p0, hi.x, lo.x); split2(p1, hi.y, lo.y);
            split2(p2, hi.z, lo.z); split2(p3, hi.w, lo.w);
            int kk = m * 16 + lg * 4;
            int addr = lm * 64 + (((kk >> 3) ^ (lm & 7)) << 3) + (kk & 7);
            *(ushort4*)&Ph[w][addr] = hi;
            *(ushort4*)&Pl[w][addr] = lo;
        }
        psum += __shfl_xor(psum, 16);
        psum += __shfl_xor(psum, 32);
        lsum = lsum * corr + psum;
        // rescale O accumulator (rows = lg*4+reg; corr lives at lane q)
        float cr0 = __shfl(corr, lg * 4 + 0);
        float cr1 = __shfl(corr, lg * 4 + 1);
        float cr2 = __shfl(corr, lg * 4 + 2);
        float cr3 = __shfl(corr, lg * 4 + 3);
        #pragma unroll
        for (int n = 0; n < 4; ++n) {
            acc[n][0] *= cr0; acc[n][1] *= cr1;
            acc[n][2] *= cr2; acc[n][3] *= cr3;
        }
        // ---- O += P @ V ----
        #pragma unroll
        for (int ks = 0; ks < 2; ++ks) {
            int ch = (ks * 4 + lg) ^ (lm & 7);
            int pidx = lm * 64 + ch * 8;
            bf16x8 pah = *(bf16x8*)&Ph[w][pidx];
            bf16x8 pal = *(bf16x8*)&Pl[w][pidx];
            #pragma unroll
            for (int n = 0; n < 4; ++n) {
                int d = n * 16 + lm;
                int vch = (ks * 4 + lg) ^ (d & 7);
                int vidx = d * 64 + vch * 8;
                bf16x8 vh = *(bf16x8*)&Vs_hi[vidx];
                bf16x8 vl = *(bf16x8*)&Vs_lo[vidx];
                acc[n] = __builtin_amdgcn_mfma_f32_16x16x32_bf16(pah, vh, acc[n], 0, 0, 0);
                acc[n] = __builtin_amdgcn_mfma_f32_16x16x32_bf16(pah, vl, acc[n], 0, 0, 0);
                acc[n] = __builtin_amdgcn_mfma_f32_16x16x32_bf16(pal, vh, acc[n], 0, 0, 0);
            }
        }
        __syncthreads();
    }

    float linv = 1.f / lsum;
    float li0 = __shfl(linv, lg * 4 + 0);
    float li1 = __shfl(linv, lg * 4 + 1);
    float li2 = __shfl(linv, lg * 4 + 2);
    float li3 = __shfl(linv, lg * 4 + 3);
    #pragma unroll
    for (int n = 0; n < 4; ++n) {
        int col = h * 64 + n * 16 + lm;
        int rbase = q0 + w * 16 + lg * 4;
        o[(size_t)(b * TT + rbase + 0) * DD + col] = acc[n][0] * li0;
        o[(size_t)(b * TT + rbase + 1) * DD + col] = acc[n][1] * li1;
        o[(size_t)(b * TT + rbase + 2) * DD + col] = acc[n][2] * li2;
        o[(size_t)(b * TT + rbase + 3) * DD + col] = acc[n][3] * li3;
    }
}

// ---------------- Vocab head ----------------
__global__ __launch_bounds__(256) void head_kernel(
    const float* __restrict__ xf, const float* __restrict__ Wh,
    const float* __restrict__ bh, float* __restrict__ out)
{
    __shared__ float x0[DD];
    __shared__ float x1[DD];
    int tid = threadIdx.x;
    for (int i = tid; i < DD; i += 256) {
        x0[i] = xf[i];
        x1[i] = xf[DD + i];
    }
    __syncthreads();
    int v = blockIdx.x * 256 + tid;
    float a0 = 0.f, a1 = 0.f, a0b = 0.f, a1b = 0.f;
    for (int d = 0; d < DD; d += 2) {
        float w0 = Wh[(size_t)d * V + v];
        float w1 = Wh[(size_t)(d + 1) * V + v];
        a0  += x0[d] * w0;     a1  += x1[d] * w0;
        a0b += x0[d + 1] * w1; a1b += x1[d + 1] * w1;
    }
    out[v]      = a0 + a0b + bh[v];
    out[V + v]  = a1 + a1b + bh[v];
}

// ---------------- Launch ----------------
extern "C" void kernel_launch(void* const* d_in, const int* in_sizes, int n_in,
                              void* d_out, int out_size, void* d_ws, size_t ws_size,
                              hipStream_t stream) {
    const int*   tokens  = (const int*)d_in[0];
    const float* te      = (const float*)d_in[1];
    const float* pe      = (const float*)d_in[2];
    const float* qkv_w   = (const float*)d_in[3];
    const float* qkv_b   = (const float*)d_in[4];
    const float* out_w   = (const float*)d_in[5];
    const float* out_b   = (const float*)d_in[6];
    const float* ln_w    = (const float*)d_in[7];
    const float* ln_b    = (const float*)d_in[8];
    const float* lnf_w   = (const float*)d_in[9];
    const float* lnf_b   = (const float*)d_in[10];
    const float* head_w  = (const float*)d_in[11];
    const float* head_b  = (const float*)d_in[12];
    float* logits = (float*)d_out;

    // workspace layout (~73 MB):
    float* h    = (float*)d_ws;                       // 2048x1024
    float* x    = h + (size_t)MM * DD;                // 2048x1024
    float* qkvb = x + (size_t)MM * DD;                // 2048x3072
    float* ob   = qkvb + (size_t)MM * 3 * DD;         // 2048x1024
    float* xfin = ob + (size_t)MM * DD;               // 2x1024
    ushort* wq_hi = (ushort*)(xfin + 2 * DD);         // 3072x1024 bf16
    ushort* wq_lo = wq_hi + (size_t)3 * DD * DD;
    ushort* wo_hi = wq_lo + (size_t)3 * DD * DD;      // 1024x1024 bf16
    ushort* wo_lo = wo_hi + (size_t)DD * DD;
    ushort* vt_hi = wo_lo + (size_t)DD * DD;          // [32][64][1024] bf16
    ushort* vt_lo = vt_hi + (size_t)BB * HH * HDIM * TT;

    embed_kernel<<<MM, 256, 0, stream>>>(tokens, te, pe, h);

    for (int l = 0; l < LL; ++l) {
        transpose_split<<<dim3(3 * DD / 64, DD / 64), 256, 0, stream>>>(
            qkv_w + (size_t)l * DD * 3 * DD, wq_hi, wq_lo, DD, 3 * DD);
        transpose_split<<<dim3(DD / 64, DD / 64), 256, 0, stream>>>(
            out_w + (size_t)l * DD * DD, wo_hi, wo_lo, DD, DD);

        ln_kernel<<<MM, 256, 0, stream>>>(h, DD, ln_w + (size_t)l * DD,
                                          ln_b + (size_t)l * DD, x, DD);
        gemm_split<<<dim3(3 * DD / 128, MM / 128), 256, 0, stream>>>(
            x, wq_hi, wq_lo, qkv_b + (size_t)l * 3 * DD, nullptr, qkvb,
            MM, 3 * DD, DD);
        v_transpose_split<<<dim3(BB * HH, TT / 64), 256, 0, stream>>>(
            qkvb, vt_hi, vt_lo);
        attn_mfma<<<dim3(BB * HH, TT / 64), 256, 0, stream>>>(
            qkvb, vt_hi, vt_lo, ob);
        gemm_split<<<dim3(DD / 128, MM / 128), 256, 0, stream>>>(
            ob, wo_hi, wo_lo, out_b + (size_t)l * DD, h, h, MM, DD, DD);
    }

    ln_kernel<<<2, 256, 0, stream>>>(h + (size_t)(TT - 1) * DD, (size_t)TT * DD,
                                     lnf_w, lnf_b, xfin, DD);
    head_kernel<<<V / 256, 256, 0, stream>>>(xfin, head_w, head_b, logits);
}